// Round 7
// baseline (164.747 us; speedup 1.0000x reference)
//
#include <hip/hip_runtime.h>
#include <hip/hip_bf16.h>
#include <stdint.h>

#define NCLS 10
#define B_ 8
#define N_ 16384
#define G_ 64
#define INF_ 1.0e8f

typedef unsigned long long u64;
typedef unsigned int u32;

__device__ __forceinline__ u32 ordf(float f) {
    u32 b = __float_as_uint(f);
    return (b & 0x80000000u) ? ~b : (b | 0x80000000u);
}
__device__ __forceinline__ float unordf(u32 u) {
    u32 b = (u & 0x80000000u) ? (u ^ 0x80000000u) : ~u;
    return __uint_as_float(b);
}

// Op-for-op identical to the validated round-1 eval (contract off).
__device__ __forceinline__ float iou_pair(float px, float pz, float g3x, float g3z) {
#pragma clang fp contract(off)
    float ddx = px - g3x;
    float ddz = pz - g3z;
    float d = sqrtf(ddx * ddx + ddz * ddz);
    float iou = 1.0f - d / 4.0f;
    return fminf(fmaxf(iou, 0.0f), 1.0f);
}

// Cost for an INSIDE pair (is_in == pad > 0). Identical op order to round 1.
__device__ __forceinline__ float cost_pair(float cx, float cy, float sx, float sy,
                                           float ps, float gcx, float gcy,
                                           float pad, float iou) {
#pragma clang fp contract(off)
    float dx = (cx - gcx) / sx;
    float dy = (cy - gcy) / sy;
    float dist = sqrtf(dx * dx + dy * dy) * pad;
    float soft = exp10f(dist - 3.0f);
    float iou_cost = -logf(iou + 1e-7f) * 3.0f;
    float e = expf(-fabsf(ps));
    float sig = (ps >= 0.0f) ? (1.0f / (1.0f + e)) : (e / (1.0f + e));
    float scale = iou - sig;
    float bce = fmaxf(ps, 0.0f) - ps * iou + log1pf(e);
    float cls = bce * (scale * scale);
    return cls + iou_cost + soft;
}

__device__ __forceinline__ u32 wave_max_u32(u32 k) {
#pragma unroll
    for (int off = 32; off >= 1; off >>= 1) {
        u32 o = __shfl_xor(k, off, 64);
        k = (o > k) ? o : k;
    }
    return k;
}
__device__ __forceinline__ u32 wave_min_u32(u32 k) {
#pragma unroll
    for (int off = 32; off >= 1; off >>= 1) {
        u32 o = __shfl_xor(k, off, 64);
        k = (o < k) ? o : k;
    }
    return k;
}

// ---------------- k1f: fused mask (odd blocks) + threshold (even blocks) ---
// mask role:    per-(b,n) inside mask via compares only -> mask64.
// thresh role:  block per (b,g): full N scan; iou top-13 + inside-only cost
//               bottom-14; per-wave extraction + wave-0 merge -> ks, thr.
//               No buckets, no atomics, no memset.
__global__ __launch_bounds__(256) void k1f(
    const float* __restrict__ priors,
    const float* __restrict__ gt_bboxes,
    const float* __restrict__ pad_flag,
    const float* __restrict__ pred_bboxes,
    const float* __restrict__ pred_scores,
    const int*   __restrict__ gt_labels,
    const float* __restrict__ gt_center,
    const float* __restrict__ gt_b3d,
    u64* __restrict__ mask64,
    float* __restrict__ thr_half)
{
    int role = blockIdx.x & 1;
    int idx  = blockIdx.x >> 1;
    int tid  = threadIdx.x;

    if (role == 1) {
        // ------- mask role: idx = 0..511 -------
        int b = idx >> 6;
        int n = ((idx & 63) << 8) | tid;
        float4 pr = ((const float4*)priors)[n];
        float cx = pr.x, cy = pr.y;
        u64 m = 0;
#pragma unroll 8
        for (int g = 0; g < G_; ++g) {
            int gi = b * G_ + g;                  // uniform
            float4 gbb = ((const float4*)gt_bboxes)[gi];
            float padv = pad_flag[gi];
            bool isin = (cx > gbb.x) && (cy > gbb.y) && (cx < gbb.z) && (cy < gbb.w)
                        && (padv > 0.0f);
            m |= ((u64)isin) << g;
        }
        mask64[(size_t)b * N_ + n] = m;
        return;
    }

    // ------- thresh role: gi = idx = 0..511 -------
    __shared__ float s_iou[4 * 13];
    __shared__ float s_cost[4 * 14];
    int gi = idx;
    int b = gi >> 6;
    int lane = tid & 63;
    int w = tid >> 6;

    float gx1 = gt_bboxes[gi * 4 + 0], gy1 = gt_bboxes[gi * 4 + 1];
    float gx2 = gt_bboxes[gi * 4 + 2], gy2 = gt_bboxes[gi * 4 + 3];
    float gcx = gt_center[gi * 2 + 0], gcy = gt_center[gi * 2 + 1];
    float g3x = gt_b3d[gi * 7 + 0],   g3z = gt_b3d[gi * 7 + 2];
    float padv = pad_flag[gi];
    int lab = gt_labels[gi];
    const float* pb = pred_bboxes + (size_t)b * N_ * 7;
    const float* sc = pred_scores + (size_t)b * N_ * 10;

    float ti[13], tc[14];
#pragma unroll
    for (int j = 0; j < 13; ++j) ti[j] = -1.0f;
#pragma unroll
    for (int j = 0; j < 14; ++j) tc[j] = INF_;

    for (int it = 0; it < 64; ++it) {
        int n = (it << 8) | tid;                  // coalesced across threads
        float4 pr = ((const float4*)priors)[n];
        float px = pb[n * 7 + 0];
        float pz = pb[n * 7 + 2];
        float iou = iou_pair(px, pz, g3x, g3z);
        if (iou > ti[12]) {
            float v = iou;
#pragma unroll
            for (int j = 0; j < 13; ++j) {
                float o = ti[j]; bool gt_ = v > o;
                float mx = gt_ ? v : o; v = gt_ ? o : v; ti[j] = mx;
            }
        }
        bool isin = (pr.x > gx1) && (pr.y > gy1) && (pr.x < gx2) && (pr.y < gy2)
                    && (padv > 0.0f);
        if (isin) {
            float ps = sc[n * 10 + lab];
            float cst = cost_pair(pr.x, pr.y, pr.z, pr.w, ps, gcx, gcy, padv, iou);
            if (cst < tc[13]) {
                float v = cst;
#pragma unroll
                for (int j = 0; j < 14; ++j) {
                    float o = tc[j]; bool lt = v < o;
                    float mn = lt ? v : o; v = lt ? o : v; tc[j] = mn;
                }
            }
        }
    }

    // per-wave top-13 extraction (descending)
    {
        float keepv = 0.0f;
        for (int r = 0; r < 13; ++r) {
            u32 mykey = ordf(ti[0]);
            u32 m = wave_max_u32(mykey);
            if (lane == r) keepv = unordf(m);
            int winner = __ffsll(__ballot(mykey == m)) - 1;
            if (lane == winner) {
#pragma unroll
                for (int j = 0; j < 12; ++j) ti[j] = ti[j + 1];
                ti[12] = -3.0e38f;
            }
        }
        if (lane < 13) s_iou[w * 13 + lane] = keepv;
    }
    // per-wave bottom-14 extraction (ascending)
    {
        float keepv = 0.0f;
        for (int r = 0; r < 14; ++r) {
            u32 mykey = ordf(tc[0]);
            u32 m = wave_min_u32(mykey);
            if (lane == r) keepv = unordf(m);
            int winner = __ffsll(__ballot(mykey == m)) - 1;
            if (lane == winner) {
#pragma unroll
                for (int j = 0; j < 13; ++j) tc[j] = tc[j + 1];
                tc[13] = 3.0e38f;
            }
        }
        if (lane < 14) s_cost[w * 14 + lane] = keepv;
    }
    __syncthreads();

    if (w == 0) {
        // merge 52 iou partials -> ks
        float vi = (lane < 52) ? s_iou[lane] : -3.0e38f;
        float sum13 = 0.0f;
        for (int r = 0; r < 13; ++r) {
            u32 mykey = ordf(vi);
            u32 m = wave_max_u32(mykey);
            sum13 += unordf(m);
            int winner = __ffsll(__ballot(mykey == m)) - 1;
            if (lane == winner) vi = -3.0e38f;
        }
        int ks = (int)sum13;
        if (ks < 1) ks = 1;

        // merge 56 cost partials -> ck, ckm1
        float vc = (lane < 56) ? s_cost[lane] : 3.0e38f;
        float ck = INF_, ckm1 = INF_;
        for (int r = 0; r < 14; ++r) {
            u32 mykey = ordf(vc);
            u32 m = wave_min_u32(mykey);
            float vm = unordf(m);
            if (r == ks - 1) ckm1 = vm;
            if (r == ks)     ck = vm;
            int winner = __ffsll(__ballot(mykey == m)) - 1;
            if (lane == winner) vc = 3.0e38f;
        }
        if (lane == 0) thr_half[gi] = 0.5f * (ck + ckm1);
    }
}

// ---------------- k2: matching compute + coalesced bit expansion ----------
// (unchanged from the round-6 passing version)
__global__ __launch_bounds__(256) void k2(
    const float* __restrict__ priors,
    const float* __restrict__ pred_bboxes,
    const float* __restrict__ pred_scores,
    const int*   __restrict__ gt_labels,
    const float* __restrict__ gt_center,
    const float* __restrict__ gt_b3d,
    const float* __restrict__ pad_flag,
    const float* __restrict__ thr_half,
    const u64*   __restrict__ mask64,
    float* __restrict__ out)
{
    __shared__ float s_gcx[G_], s_gcy[G_], s_g3x[G_], s_g3z[G_];
    __shared__ float s_pad[G_], s_thr[G_];
    __shared__ int   s_lab[G_];
    __shared__ u64   s_words[256];

    int b = blockIdx.x >> 6;
    int n0b = (blockIdx.x & 63) << 8;          // first prior of this block
    int n = n0b | threadIdx.x;
    size_t t = (size_t)b * N_ + n;

    if (threadIdx.x < G_) {
        int gi = b * G_ + threadIdx.x;
        s_gcx[threadIdx.x] = gt_center[gi * 2 + 0];
        s_gcy[threadIdx.x] = gt_center[gi * 2 + 1];
        s_g3x[threadIdx.x] = gt_b3d[gi * 7 + 0];
        s_g3z[threadIdx.x] = gt_b3d[gi * 7 + 2];
        s_pad[threadIdx.x] = pad_flag[gi];
        s_thr[threadIdx.x] = thr_half[gi];
        s_lab[threadIdx.x] = gt_labels[gi];
    }
    __syncthreads();

    const float* pb = pred_bboxes + (size_t)b * N_ * 7;
    const float* sc = pred_scores + (size_t)b * N_ * 10;
    float4 pr = ((const float4*)priors)[n];
    float px = pb[n * 7 + 0];
    float pz = pb[n * 7 + 2];

    // init = g 0 (argmin over all-INF costs returns index 0)
    float iouC = iou_pair(px, pz, s_g3x[0], s_g3z[0]);
    float costC = INF_;
    int   labC = s_lab[0];

    float iouM = 0.0f, costM = 3.0e38f;
    int   labM = 0, argM = 0;
    u64 mmatch = 0;

    u64 m = mask64[t];
    while (m) {
        int g = __ffsll(m) - 1;
        m &= m - 1;
        float gcx = s_gcx[g], gcy = s_gcy[g];
        float g3x = s_g3x[g], g3z = s_g3z[g];
        float padg = s_pad[g];
        int   labg = s_lab[g];
        float th = s_thr[g];
        float ps = sc[n * 10 + labg];
        float iou = iou_pair(px, pz, g3x, g3z);
        float c = cost_pair(pr.x, pr.y, pr.z, pr.w, ps, gcx, gcy, padg, iou);
        if (c < costC) { costC = c; iouC = iou; labC = labg; }
        if (c <= th * padg) {
            mmatch |= 1ull << g;
            if (c < costM) { costM = c; iouM = iou; labM = labg; argM = g; }
        }
    }
    int cm = __popcll(mmatch);
    bool matched = cm > 0;
    u64 outm = (cm > 1) ? (1ull << argM) : mmatch;
    float metric = matched ? iouM : iouC;
    float olab = matched ? (float)labM
                         : ((iouC < 1e-7f) ? (float)NCLS : (float)labC);

    float* out_lab = out;
    float* out_w   = out + (size_t)B_ * N_;
    float* out_met = out + (size_t)2 * B_ * N_;
    float* out_mat = out + (size_t)3 * B_ * N_;
    out_lab[t] = olab;
    out_w[t]   = 1.0f;
    out_met[t] = metric;
    s_words[threadIdx.x] = outm;
    __syncthreads();

    // Phase 2: expand 256 words -> 256 rows x 64 floats, coalesced.
    int q  = threadIdx.x & 3;                  // 16-col quarter
    int r0 = threadIdx.x >> 2;                 // base row 0..63
    size_t rowbase = (size_t)b * N_ + n0b;
#pragma unroll
    for (int it = 0; it < 4; ++it) {
        int row = r0 + (it << 6);
        u64 wv = s_words[row];
        u32 bits = (u32)(wv >> (q * 16)) & 0xffffu;
        float* dst = out_mat + (rowbase + row) * 64 + q * 16;
#pragma unroll
        for (int jj = 0; jj < 4; ++jj) {
            float4 f;
            f.x = (bits >> (jj * 4 + 0)) & 1u ? 1.0f : 0.0f;
            f.y = (bits >> (jj * 4 + 1)) & 1u ? 1.0f : 0.0f;
            f.z = (bits >> (jj * 4 + 2)) & 1u ? 1.0f : 0.0f;
            f.w = (bits >> (jj * 4 + 3)) & 1u ? 1.0f : 0.0f;
            ((float4*)dst)[jj] = f;
        }
    }
}

extern "C" void kernel_launch(void* const* d_in, const int* in_sizes, int n_in,
                              void* d_out, int out_size, void* d_ws, size_t ws_size,
                              hipStream_t stream)
{
    const float* pred_bboxes = (const float*)d_in[0];
    const float* pred_scores = (const float*)d_in[1];
    const float* priors      = (const float*)d_in[2];
    const int*   gt_labels   = (const int*)d_in[3];
    const float* gt_bboxes   = (const float*)d_in[4];
    const float* gt_center   = (const float*)d_in[5];
    const float* gt_b3d      = (const float*)d_in[6];
    const float* pad_flag    = (const float*)d_in[7];
    float* out = (float*)d_out;

    // ws layout (bytes): mask64 (131072*8 = 1048576) + thr_half (512*4)
    char* ws = (char*)d_ws;
    u64* mask64     = (u64*)ws;
    float* thr_half = (float*)(ws + 1048576);

    k1f<<<1024, 256, 0, stream>>>(priors, gt_bboxes, pad_flag, pred_bboxes,
                                  pred_scores, gt_labels, gt_center, gt_b3d,
                                  mask64, thr_half);
    k2<<<512, 256, 0, stream>>>(priors, pred_bboxes, pred_scores, gt_labels,
                                gt_center, gt_b3d, pad_flag,
                                thr_half, mask64, out);
}

// Round 8
// 81.677 us; speedup vs baseline: 2.0171x; 2.0171x over previous
//
#include <hip/hip_runtime.h>
#include <hip/hip_bf16.h>
#include <stdint.h>

#define NCLS 10
#define B_ 8
#define N_ 16384
#define G_ 64
#define INF_ 1.0e8f

typedef unsigned long long u64;
typedef unsigned int u32;

__device__ __forceinline__ u32 ordf(float f) {
    u32 b = __float_as_uint(f);
    return (b & 0x80000000u) ? ~b : (b | 0x80000000u);
}
__device__ __forceinline__ float unordf(u32 u) {
    u32 b = (u & 0x80000000u) ? (u ^ 0x80000000u) : ~u;
    return __uint_as_float(b);
}

// Op-for-op identical to the validated round-1 eval (contract off).
__device__ __forceinline__ float iou_pair(float px, float pz, float g3x, float g3z) {
#pragma clang fp contract(off)
    float ddx = px - g3x;
    float ddz = pz - g3z;
    float d = sqrtf(ddx * ddx + ddz * ddz);
    float iou = 1.0f - d / 4.0f;
    return fminf(fmaxf(iou, 0.0f), 1.0f);
}

// Cost for an INSIDE pair (is_in == pad > 0). Identical op order to round 1.
__device__ __forceinline__ float cost_pair(float cx, float cy, float sx, float sy,
                                           float ps, float gcx, float gcy,
                                           float pad, float iou) {
#pragma clang fp contract(off)
    float dx = (cx - gcx) / sx;
    float dy = (cy - gcy) / sy;
    float dist = sqrtf(dx * dx + dy * dy) * pad;
    float soft = exp10f(dist - 3.0f);
    float iou_cost = -logf(iou + 1e-7f) * 3.0f;
    float e = expf(-fabsf(ps));
    float sig = (ps >= 0.0f) ? (1.0f / (1.0f + e)) : (e / (1.0f + e));
    float scale = iou - sig;
    float bce = fmaxf(ps, 0.0f) - ps * iou + log1pf(e);
    float cls = bce * (scale * scale);
    return cls + iou_cost + soft;
}

__device__ __forceinline__ u32 wave_max_u32(u32 k) {
#pragma unroll
    for (int off = 32; off >= 1; off >>= 1) {
        u32 o = __shfl_xor(k, off, 64);
        k = (o > k) ? o : k;
    }
    return k;
}
__device__ __forceinline__ u32 wave_min_u32(u32 k) {
#pragma unroll
    for (int off = 32; off >= 1; off >>= 1) {
        u32 o = __shfl_xor(k, off, 64);
        k = (o < k) ? o : k;
    }
    return k;
}

// ---------------- k_ab: interleaved mask+transpose (1 in 5) + k1b (4 in 5) --
// mask role: per-(b,n) inside mask -> mask64 (n-major, for k2) AND, via one
//            __ballot per g, bitmapT (g-major bitmap, for k1c). Zero atomics.
// k1b role:  per-(b,g,chunk of 1024) iou top-13 via per-lane Batcher sort-16
//            + 13-round u32-key extraction.
__global__ __launch_bounds__(256) void k_ab(
    const float* __restrict__ priors,
    const float* __restrict__ gt_bboxes,
    const float* __restrict__ pad_flag,
    const float* __restrict__ pred_bboxes,
    const float* __restrict__ gt_b3d,
    u64* __restrict__ mask64,
    u64* __restrict__ bitmapT,
    float* __restrict__ iou13)
{
    u32 r5 = blockIdx.x % 5u, q5 = blockIdx.x / 5u;
    int tid = threadIdx.x;
    int lane = tid & 63;
    if (r5 == 4u) {
        // ------- mask+transpose role (q5 = 0..511) -------
        int b = q5 >> 6;
        int n = ((q5 & 63) << 8) | tid;
        u32 wword = ((q5 & 63) << 2) | (u32)(tid >> 6);   // word index 0..255
        float4 pr = ((const float4*)priors)[n];
        float cx = pr.x, cy = pr.y;
        u64 m = 0;
        for (int g = 0; g < G_; ++g) {
            int gi = b * G_ + g;                  // uniform
            float4 gbb = ((const float4*)gt_bboxes)[gi];
            float padv = pad_flag[gi];
            bool isin = (cx > gbb.x) && (cy > gbb.y) && (cx < gbb.z) && (cy < gbb.w)
                        && (padv > 0.0f);
            m |= ((u64)isin) << g;
            u64 bal = __ballot(isin);
            if (lane == 0) bitmapT[(((size_t)gi) << 8) | wword] = bal;
        }
        mask64[(size_t)b * N_ + n] = m;
    } else {
        // ------- k1b role (c = 0..2047, 4 waves each => wid 0..8191) -------
        int c = (int)(q5 * 4u + r5);
        int wid = (c << 2) | (tid >> 6);
        int b = wid >> 10;
        int g = (wid >> 4) & 63;
        int chunk = wid & 15;
        int gi = b * G_ + g;
        float g3x = gt_b3d[gi * 7 + 0];
        float g3z = gt_b3d[gi * 7 + 2];
        const float* pb = pred_bboxes + (size_t)b * N_ * 7;

        float s[16];
        int n0 = chunk * 1024 + lane;
#pragma unroll
        for (int it = 0; it < 16; ++it) {
            int n = n0 + it * 64;
            s[it] = iou_pair(pb[n * 7 + 0], pb[n * 7 + 2], g3x, g3z);
        }
        // Batcher odd-even mergesort, 16 elems, descending (max-first cswap).
#pragma unroll
        for (int p = 1; p < 16; p <<= 1) {
#pragma unroll
            for (int k = p; k >= 1; k >>= 1) {
#pragma unroll
                for (int j = k % p; j <= 15 - k; j += 2 * k) {
#pragma unroll
                    for (int i = 0; i < k; ++i) {
                        if (i + j + k <= 15) {
                            if ((i + j) / (2 * p) == (i + j + k) / (2 * p)) {
                                float hi = fmaxf(s[i + j], s[i + j + k]);
                                float lo = fminf(s[i + j], s[i + j + k]);
                                s[i + j] = hi; s[i + j + k] = lo;
                            }
                        }
                    }
                }
            }
        }
        // 13-round extraction: u32 key, ballot winner (lowest lane on tie).
        float keepv = 0.0f;
        for (int r = 0; r < 13; ++r) {
            u32 mykey = ordf(s[0]);
            u32 m = wave_max_u32(mykey);
            if (lane == r) keepv = unordf(m);
            int winner = __ffsll(__ballot(mykey == m)) - 1;
            if (lane == winner) {
#pragma unroll
                for (int j = 0; j < 13; ++j) s[j] = s[j + 1];
            }
        }
        if (lane < 13) iou13[(size_t)gi * 208 + chunk * 13 + lane] = keepv;
    }
}

// ---------------- k1c: per-(b,g) finalize (ks + threshold) ----------------
// One wave per (b,g): merge 16x13 iou partials -> ks; dense cost eval over
// set bits of the g-major bitmap (every eval needed) -> bottom-14 -> thr.
__global__ __launch_bounds__(64) void k1c(
    const float* __restrict__ iou13,
    const u64*   __restrict__ bitmapT,
    const float* __restrict__ priors,
    const float* __restrict__ pred_bboxes,
    const float* __restrict__ pred_scores,
    const int*   __restrict__ gt_labels,
    const float* __restrict__ gt_center,
    const float* __restrict__ gt_b3d,
    const float* __restrict__ pad_flag,
    float* __restrict__ thr_half)
{
    int gi = blockIdx.x;
    int lane = threadIdx.x;
    int b = gi >> 6;

    // (i) top-13 iou sum over 208 partials; 4 per lane, sorted desc.
    const float* base = iou13 + (size_t)gi * 208;
    float v0 = base[lane];
    float v1 = base[64 + lane];
    float v2 = base[128 + lane];
    float v3 = (lane < 16) ? base[192 + lane] : -3.0e38f;
    { float h = fmaxf(v0, v1), l = fminf(v0, v1); v0 = h; v1 = l; }
    { float h = fmaxf(v2, v3), l = fminf(v2, v3); v2 = h; v3 = l; }
    { float h = fmaxf(v0, v2), l = fminf(v0, v2); v0 = h; v2 = l; }
    { float h = fmaxf(v1, v3), l = fminf(v1, v3); v1 = h; v3 = l; }
    { float h = fmaxf(v1, v2), l = fminf(v1, v2); v1 = h; v2 = l; }
    float sum13 = 0.0f;
    for (int r = 0; r < 13; ++r) {
        u32 mykey = ordf(v0);
        u32 m = wave_max_u32(mykey);
        sum13 += unordf(m);
        int winner = __ffsll(__ballot(mykey == m)) - 1;
        if (lane == winner) { v0 = v1; v1 = v2; v2 = v3; v3 = -3.0e38f; }
    }
    int ks = (int)sum13;
    if (ks < 1) ks = 1;

    // (ii) dense cost eval over set bits of this gi's bitmap, bottom-14
    float gcx = gt_center[gi * 2 + 0], gcy = gt_center[gi * 2 + 1];
    float g3x = gt_b3d[gi * 7 + 0],   g3z = gt_b3d[gi * 7 + 2];
    float padv = pad_flag[gi];
    int lab = gt_labels[gi];
    const float* pb = pred_bboxes + (size_t)b * N_ * 7;
    const float* sc = pred_scores + (size_t)b * N_ * 10;

    float l[14];
#pragma unroll
    for (int j = 0; j < 14; ++j) l[j] = INF_;
#pragma unroll
    for (int j = 0; j < 4; ++j) {
        u32 w = (u32)(lane + 64 * j);
        u64 wv = bitmapT[(((size_t)gi) << 8) | w];   // coalesced
        u32 nb = w << 6;
        while (wv) {
            int bit = __ffsll(wv) - 1;
            wv &= wv - 1;
            int n = (int)(nb | (u32)bit);
            float4 pr = ((const float4*)priors)[n];
            float px = pb[n * 7 + 0];
            float pz = pb[n * 7 + 2];
            float ps = sc[n * 10 + lab];
            float iou = iou_pair(px, pz, g3x, g3z);
            float cst = cost_pair(pr.x, pr.y, pr.z, pr.w, ps, gcx, gcy, padv, iou);
            if (cst < l[13]) {
                float v = cst;
#pragma unroll
                for (int jj = 0; jj < 14; ++jj) {
                    float o = l[jj]; bool lt = v < o;
                    float mn = lt ? v : o; v = lt ? o : v; l[jj] = mn;
                }
            }
        }
    }
    float ck = INF_, ckm1 = INF_;
    for (int r = 0; r < 14; ++r) {
        u32 mykey = ordf(l[0]);
        u32 m = wave_min_u32(mykey);
        float vm = unordf(m);
        if (r == ks - 1) ckm1 = vm;
        if (r == ks)     ck = vm;
        int winner = __ffsll(__ballot(mykey == m)) - 1;
        if (lane == winner) {
#pragma unroll
            for (int j = 0; j < 13; ++j) l[j] = l[j + 1];
            l[13] = INF_;
        }
    }
    if (lane == 0) thr_half[gi] = 0.5f * (ck + ckm1);
}

// ---------------- k2: matching compute + coalesced bit expansion ----------
// (unchanged from the round-6 passing version)
__global__ __launch_bounds__(256) void k2(
    const float* __restrict__ priors,
    const float* __restrict__ pred_bboxes,
    const float* __restrict__ pred_scores,
    const int*   __restrict__ gt_labels,
    const float* __restrict__ gt_center,
    const float* __restrict__ gt_b3d,
    const float* __restrict__ pad_flag,
    const float* __restrict__ thr_half,
    const u64*   __restrict__ mask64,
    float* __restrict__ out)
{
    __shared__ float s_gcx[G_], s_gcy[G_], s_g3x[G_], s_g3z[G_];
    __shared__ float s_pad[G_], s_thr[G_];
    __shared__ int   s_lab[G_];
    __shared__ u64   s_words[256];

    int b = blockIdx.x >> 6;
    int n0b = (blockIdx.x & 63) << 8;          // first prior of this block
    int n = n0b | threadIdx.x;
    size_t t = (size_t)b * N_ + n;

    if (threadIdx.x < G_) {
        int gi = b * G_ + threadIdx.x;
        s_gcx[threadIdx.x] = gt_center[gi * 2 + 0];
        s_gcy[threadIdx.x] = gt_center[gi * 2 + 1];
        s_g3x[threadIdx.x] = gt_b3d[gi * 7 + 0];
        s_g3z[threadIdx.x] = gt_b3d[gi * 7 + 2];
        s_pad[threadIdx.x] = pad_flag[gi];
        s_thr[threadIdx.x] = thr_half[gi];
        s_lab[threadIdx.x] = gt_labels[gi];
    }
    __syncthreads();

    const float* pb = pred_bboxes + (size_t)b * N_ * 7;
    const float* sc = pred_scores + (size_t)b * N_ * 10;
    float4 pr = ((const float4*)priors)[n];
    float px = pb[n * 7 + 0];
    float pz = pb[n * 7 + 2];

    // init = g 0 (argmin over all-INF costs returns index 0)
    float iouC = iou_pair(px, pz, s_g3x[0], s_g3z[0]);
    float costC = INF_;
    int   labC = s_lab[0];

    float iouM = 0.0f, costM = 3.0e38f;
    int   labM = 0, argM = 0;
    u64 mmatch = 0;

    u64 m = mask64[t];
    while (m) {
        int g = __ffsll(m) - 1;
        m &= m - 1;
        float gcx = s_gcx[g], gcy = s_gcy[g];
        float g3x = s_g3x[g], g3z = s_g3z[g];
        float padg = s_pad[g];
        int   labg = s_lab[g];
        float th = s_thr[g];
        float ps = sc[n * 10 + labg];
        float iou = iou_pair(px, pz, g3x, g3z);
        float c = cost_pair(pr.x, pr.y, pr.z, pr.w, ps, gcx, gcy, padg, iou);
        if (c < costC) { costC = c; iouC = iou; labC = labg; }
        if (c <= th * padg) {
            mmatch |= 1ull << g;
            if (c < costM) { costM = c; iouM = iou; labM = labg; argM = g; }
        }
    }
    int cm = __popcll(mmatch);
    bool matched = cm > 0;
    u64 outm = (cm > 1) ? (1ull << argM) : mmatch;
    float metric = matched ? iouM : iouC;
    float olab = matched ? (float)labM
                         : ((iouC < 1e-7f) ? (float)NCLS : (float)labC);

    float* out_lab = out;
    float* out_w   = out + (size_t)B_ * N_;
    float* out_met = out + (size_t)2 * B_ * N_;
    float* out_mat = out + (size_t)3 * B_ * N_;
    out_lab[t] = olab;
    out_w[t]   = 1.0f;
    out_met[t] = metric;
    s_words[threadIdx.x] = outm;
    __syncthreads();

    // Phase 2: expand 256 words -> 256 rows x 64 floats, coalesced.
    int q  = threadIdx.x & 3;                  // 16-col quarter
    int r0 = threadIdx.x >> 2;                 // base row 0..63
    size_t rowbase = (size_t)b * N_ + n0b;
#pragma unroll
    for (int it = 0; it < 4; ++it) {
        int row = r0 + (it << 6);
        u64 wv = s_words[row];
        u32 bits = (u32)(wv >> (q * 16)) & 0xffffu;
        float* dst = out_mat + (rowbase + row) * 64 + q * 16;
#pragma unroll
        for (int jj = 0; jj < 4; ++jj) {
            float4 f;
            f.x = (bits >> (jj * 4 + 0)) & 1u ? 1.0f : 0.0f;
            f.y = (bits >> (jj * 4 + 1)) & 1u ? 1.0f : 0.0f;
            f.z = (bits >> (jj * 4 + 2)) & 1u ? 1.0f : 0.0f;
            f.w = (bits >> (jj * 4 + 3)) & 1u ? 1.0f : 0.0f;
            ((float4*)dst)[jj] = f;
        }
    }
}

extern "C" void kernel_launch(void* const* d_in, const int* in_sizes, int n_in,
                              void* d_out, int out_size, void* d_ws, size_t ws_size,
                              hipStream_t stream)
{
    const float* pred_bboxes = (const float*)d_in[0];
    const float* pred_scores = (const float*)d_in[1];
    const float* priors      = (const float*)d_in[2];
    const int*   gt_labels   = (const int*)d_in[3];
    const float* gt_bboxes   = (const float*)d_in[4];
    const float* gt_center   = (const float*)d_in[5];
    const float* gt_b3d      = (const float*)d_in[6];
    const float* pad_flag    = (const float*)d_in[7];
    float* out = (float*)d_out;

    // ws layout (bytes):
    char* ws = (char*)d_ws;
    u64* mask64   = (u64*)ws;                              // 131072*8 = 1048576
    u64* bitmapT  = (u64*)(ws + 1048576);                  // 512*256*8 = 1048576
    float* iou13  = (float*)(ws + 2097152);                // 512*208*4 = 425984
    float* thr_half = (float*)(ws + 2097152 + 425984);     // 512*4

    k_ab<<<2560, 256, 0, stream>>>(priors, gt_bboxes, pad_flag, pred_bboxes,
                                   gt_b3d, mask64, bitmapT, iou13);
    k1c<<<512, 64, 0, stream>>>(iou13, bitmapT, priors, pred_bboxes,
                                pred_scores, gt_labels, gt_center, gt_b3d,
                                pad_flag, thr_half);
    k2<<<512, 256, 0, stream>>>(priors, pred_bboxes, pred_scores, gt_labels,
                                gt_center, gt_b3d, pad_flag,
                                thr_half, mask64, out);
}